// Round 8
// baseline (944.346 us; speedup 1.0000x reference)
//
#include <hip/hip_runtime.h>

typedef short bf16x8 __attribute__((ext_vector_type(8)));
typedef float f32x4 __attribute__((ext_vector_type(4)));

__device__ __forceinline__ unsigned short f2b(float f) {
    unsigned int u = __builtin_bit_cast(unsigned int, f);
    u += 0x7fffu + ((u >> 16) & 1u);   // RNE
    return (unsigned short)(u >> 16);
}
__device__ __forceinline__ float b2f(unsigned short s) {
    unsigned int u = ((unsigned int)s) << 16;
    return __builtin_bit_cast(float, u);
}

// wt[k][i][j] = bf16(w1[j][k][i]);  k<3, i<128, j<64
__global__ void wt_prepass(const float* __restrict__ w1, unsigned short* __restrict__ wt) {
    int t = blockIdx.x * 256 + threadIdx.x;
    if (t >= 24576) return;
    int j = t & 63;
    int i = (t >> 6) & 127;
    int k = t >> 13;
    wt[t] = f2b(w1[(j * 3 + k) * 128 + i]);
}

// xs: row = a*13 + s; byte = (row<<7) + ((j*2) ^ ((row&7)<<4))   [rows 0..363]
// t4s: [ic 0..127][cl 0..7][ap 0..27] u16, byte = ic*464 + cl*58 + ap*2  (59,392 B)
// barrier idiom: per-wave s_waitcnt lgkmcnt(0) + raw s_barrier (keeps global prefetch in flight)

__global__ __launch_bounds__(256, 2) void fused_main(
        const float* __restrict__ x, const float* __restrict__ w0,
        const unsigned short* __restrict__ wt, float* __restrict__ y) {
    __shared__ __align__(16) char smem[128 * 464];   // 59,392 B: xs (46.6K) then t4s
    __shared__ float w0s[256];

    const int tid  = threadIdx.x;
    const int lane = tid & 63;
    const int w    = tid >> 6;
    const int rl   = lane & 15;
    const int jb0  = (lane >> 4) << 3;

    // persistent mapping: blk = s*8 + xcd ; bc fixed per block; 8 b's per block.
    // siblings of b (bc=0..3) sit on the same XCD at the same u-step.
    const int blk   = (int)blockIdx.x;       // 512 blocks = 2/CU, all co-resident
    const int xcd   = blk & 7;
    const int sgrp  = blk >> 3;              // 0..63
    const int bc    = sgrp & 3;
    const int bslot = sgrp >> 2;             // 0..15
    const int c0    = 7 * bc;
    const int bBase = (xcd << 7) + (bslot << 3);   // 8 consecutive b's

    w0s[tid] = w0[tid];

    int q0, q1, q2;
    if      (bc == 0) { q0 = 0; q1 = 1; q2 = 6; }
    else if (bc == 1) { q0 = 1; q1 = 2; q2 = 3; }
    else if (bc == 2) { q0 = 3; q1 = 4; q2 = 5; }
    else              { q0 = 4; q1 = 5; q2 = 6; }

    const int cl = rl & 7;
    const int rh = rl >> 3;
    int rowoff[3];
#pragma unroll
    for (int k = 0; k < 3; ++k) {
        int sIdx = (bc == 0) ? ((cl == 0) ? (9 + k) : (cl - 1 + k)) : (cl + k);
        rowoff[k] = rh * 13 + sIdx;
    }

    // prologue: load unit 0
    float4 buf[21];
    {
        const float* xb = x + (size_t)bBase * 50176;
#pragma unroll
        for (int it = 0; it < 21; ++it) {
            int f = tid + (it << 8);
            int R = f / 3, q3 = f - R * 3;
            int q = (q3 == 0) ? q0 : ((q3 == 1) ? q1 : q2);
            buf[it] = *reinterpret_cast<const float4*>(xb + R * 28 + (q << 2));
        }
    }

    for (int u = 0; u < 8; ++u) {
        const int b = bBase + u;

        // ---- zero-fill halo slots (bc0: s=0,11 ; bc3: s=9) ----
        if (bc == 0 || bc == 3) {
            int nh = (bc == 0) ? 2 : 1;
            for (int idx = tid; idx < nh * 224; idx += 256) {
                int rr = idx, sl;
                if (bc == 0) { if (rr >= 224) { sl = 11; rr -= 224; } else sl = 0; }
                else sl = 9;
                int a = rr >> 3, ch = rr & 7;
                int row  = a * 13 + sl;
                int byte = (row << 7) + ((ch << 4) ^ ((row & 7) << 4));
                *reinterpret_cast<f32x4*>(smem + byte) = f32x4{0.f, 0.f, 0.f, 0.f};
            }
        }

        // ---- scatter buf -> xs ----
#pragma unroll
        for (int it = 0; it < 21; ++it) {
            int f = tid + (it << 8);
            int R = f / 3, q3 = f - R * 3;
            int q = (q3 == 0) ? q0 : ((q3 == 1) ? q1 : q2);
            int a = R % 28;
            int j2 = (R / 28) << 1;
            float vv[4] = {buf[it].x, buf[it].y, buf[it].z, buf[it].w};
#pragma unroll
            for (int e = 0; e < 4; ++e) {
                int n = (q << 2) + e;
                int sl; bool ok;
                if (bc == 0) {
                    if (n < 8)        { sl = n + 1;  ok = true; }
                    else if (n >= 26) { sl = n - 17; ok = true; }
                    else              { sl = 0;      ok = false; }
                } else {
                    sl = n + 2 - c0;
                    ok = (unsigned)sl < 10u;
                }
                if (ok) {
                    int row  = a * 13 + sl;
                    int byte = (row << 7) + (j2 ^ ((row & 7) << 4));
                    *(unsigned short*)(smem + byte) = f2b(vv[e]);
                }
            }
        }

        // ---- issue next unit's loads (stay in flight across raw barriers) ----
        if (u < 7) {
            const float* xb = x + (size_t)(b + 1) * 50176;
#pragma unroll
            for (int it = 0; it < 21; ++it) {
                int f = tid + (it << 8);
                int R = f / 3, q3 = f - R * 3;
                int q = (q3 == 0) ? q0 : ((q3 == 1) ? q1 : q2);
                buf[it] = *reinterpret_cast<const float4*>(xb + R * 28 + (q << 2));
            }
        }

        asm volatile("s_waitcnt lgkmcnt(0)" ::: "memory");
        __builtin_amdgcn_s_barrier();                      // xs ready; vmcnt NOT drained

        // ---- K-loop: per wave 14 m-tiles x 2 n-tiles, 6 K-steps of 32 ----
        f32x4 acc[14][2];
#pragma unroll
        for (int mt = 0; mt < 14; ++mt) {
            acc[mt][0] = f32x4{0.f, 0.f, 0.f, 0.f};
            acc[mt][1] = f32x4{0.f, 0.f, 0.f, 0.f};
        }
#pragma unroll
        for (int s = 0; s < 6; ++s) {
            const int k  = s >> 1;
            const int jb = ((s & 1) << 5) + jb0;
            const int jx = jb << 1;
            bf16x8 bA = *reinterpret_cast<const bf16x8*>(wt + (k << 13) + (((w << 5) + rl) << 6) + jb);
            bf16x8 bB = *reinterpret_cast<const bf16x8*>(wt + (k << 13) + (((w << 5) + 16 + rl) << 6) + jb);
#pragma unroll
            for (int mt = 0; mt < 14; ++mt) {
                int row  = 26 * mt + rowoff[k];
                int byte = (row << 7) + (jx ^ ((row & 7) << 4));
                bf16x8 af = *reinterpret_cast<const bf16x8*>(smem + byte);
                acc[mt][0] = __builtin_amdgcn_mfma_f32_16x16x32_bf16(af, bA, acc[mt][0], 0, 0, 0);
                acc[mt][1] = __builtin_amdgcn_mfma_f32_16x16x32_bf16(af, bB, acc[mt][1], 0, 0, 0);
            }
        }
        asm volatile("s_waitcnt lgkmcnt(0)" ::: "memory");
        __builtin_amdgcn_s_barrier();                      // xs reads done; t4s may overlay

        // ---- epilogue: t4s[ic][cl][ap] ----
        {
            const int rq  = (lane >> 4) << 2;
            const int icb = (w << 5) + rl;
#pragma unroll
            for (int mt = 0; mt < 14; ++mt) {
                int rbase = (mt << 4) + rq;
                int a2    = (rbase >> 3) << 1;
                int clb   = rbase & 7;
#pragma unroll
                for (int p = 0; p < 2; ++p) {
                    int ic   = icb + (p << 4);
                    int base = ic * 464 + a2;
#pragma unroll
                    for (int q = 0; q < 4; ++q) {
                        *(unsigned short*)(smem + base + (clb + q) * 58) = f2b(acc[mt][p][q]);
                    }
                }
            }
        }
        asm volatile("s_waitcnt lgkmcnt(0)" ::: "memory");
        __builtin_amdgcn_s_barrier();                      // t4s ready

        // ---- combine with w0, coalesced y store ----
        for (int f = tid; f < 6272; f += 256) {
            int lq    = f % 7;
            int t1    = f / 7;
            int m_loc = t1 % 7;
            int iloc  = t1 / 7;
            float w00 = w0s[2 * iloc], w01 = w0s[2 * iloc + 1];
            int m     = c0 + m_loc;
            int base1 = iloc * 464 + (m_loc + 1) * 58;   // c = m
            int base2 = iloc * 464 + m_loc * 58;         // c = m-1
            float ov[4];
#pragma unroll
            for (int uu = 0; uu < 4; ++uu) {
                int l  = (lq << 2) + uu;
                int ap = (l == 0) ? 27 : (l - 1);
                float v1 = b2f(*(unsigned short*)(smem + base1 + (ap << 1)));
                float v2 = b2f(*(unsigned short*)(smem + base2 + (ap << 1)));
                ov[uu] = w00 * v1 + w01 * v2;
            }
            float4 o; o.x = ov[0]; o.y = ov[1]; o.z = ov[2]; o.w = ov[3];
            *reinterpret_cast<float4*>(y + ((((size_t)b * 128 + iloc) * 28 + m) * 28) + (lq << 2)) = o;
        }
        asm volatile("s_waitcnt lgkmcnt(0)" ::: "memory");
        __builtin_amdgcn_s_barrier();                      // t4s reads done before next scatter
    }
}

extern "C" void kernel_launch(void* const* d_in, const int* in_sizes, int n_in,
                              void* d_out, int out_size, void* d_ws, size_t ws_size,
                              hipStream_t stream) {
    const float* x  = (const float*)d_in[0];
    const float* w0 = (const float*)d_in[1];
    const float* w1 = (const float*)d_in[2];
    float* y = (float*)d_out;
    unsigned short* wt = (unsigned short*)d_ws;   // 24576 u16 = 48 KiB

    hipLaunchKernelGGL(wt_prepass, dim3(96), dim3(256), 0, stream, w1, wt);
    hipLaunchKernelGGL(fused_main, dim3(512), dim3(256), 0, stream, x, w0, wt, y);
}

// Round 10
// 175.863 us; speedup vs baseline: 5.3698x; 5.3698x over previous
//
#include <hip/hip_runtime.h>

typedef short bf16x8 __attribute__((ext_vector_type(8)));
typedef float f32x4 __attribute__((ext_vector_type(4)));
typedef unsigned short u16x4 __attribute__((ext_vector_type(4)));

__device__ __forceinline__ unsigned short f2b(float f) {
    unsigned int u = __builtin_bit_cast(unsigned int, f);
    u += 0x7fffu + ((u >> 16) & 1u);   // RNE
    return (unsigned short)(u >> 16);
}
__device__ __forceinline__ float b2f(unsigned short s) {
    unsigned int u = ((unsigned int)s) << 16;
    return __builtin_bit_cast(float, u);
}

// wt[k][i][j] = bf16(w1[j][k][i]);  k<3, i<128, j<64
__global__ void wt_prepass(const float* __restrict__ w1, unsigned short* __restrict__ wt) {
    int t = blockIdx.x * 256 + threadIdx.x;
    if (t >= 24576) return;
    int j = t & 63;
    int i = (t >> 6) & 127;
    int k = t >> 13;
    wt[t] = f2b(w1[(j * 3 + k) * 128 + i]);
}

// xs: row = a*13 + s; byte = (row<<7) + ((j*2) ^ ((row&7)<<4))   [rows 0..363, 46592 B]
// t4s: [ic][cl][l] u16, byte = ic*512 + cl*64 + ((l*2) ^ (((ic*7+cl)&7)<<3))  [65536 B]
//   l = a+1 mod 28 applied at WRITE time; XOR scoped to l-dim -> injective.

__global__ __launch_bounds__(256, 2) void fused_main(
        const float* __restrict__ x, const float* __restrict__ w0,
        const unsigned short* __restrict__ wt, float* __restrict__ y) {
    __shared__ __align__(16) char smem[65536];   // xs (46.6K) then t4s (64K)
    __shared__ float w0s[256];

    const int tid  = threadIdx.x;
    const int lane = tid & 63;
    const int w    = tid >> 6;
    const int rl   = lane & 15;
    const int jb0  = (lane >> 4) << 3;

    // same-XCD sibling mapping (bc-siblings of one b are 8 dispatch-slots apart)
    const int B   = (int)blockIdx.x;
    const int b   = ((B & 7) << 7) + ((B >> 3) >> 2);
    const int bc  = (B >> 3) & 3;
    const int c0  = 7 * bc;

    w0s[tid] = w0[tid];

    // ---- zero-fill halo slots (bc0: s=0,11 ; bc3: s=9) ----
    {
        int nh = (bc == 0) ? 2 : ((bc == 3) ? 1 : 0);
        for (int idx = tid; idx < nh * 224; idx += 256) {
            int rr = idx;
            int sl;
            if (bc == 0) {
                if (rr >= 224) { sl = 11; rr -= 224; } else sl = 0;
            } else {
                sl = 9;                 // bc == 3
            }
            int a   = rr >> 3, ch = rr & 7;
            int row = a * 13 + sl;
            int byte = (row << 7) + ((ch << 4) ^ ((row & 7) << 4));
            *reinterpret_cast<f32x4*>(smem + byte) = f32x4{0.f, 0.f, 0.f, 0.f};
        }
    }

    // ---- staging: 3 batches of 7 independent float4 loads -> scatter ----
    int q0, q1, q2;
    if      (bc == 0) { q0 = 0; q1 = 1; q2 = 6; }
    else if (bc == 1) { q0 = 1; q1 = 2; q2 = 3; }
    else if (bc == 2) { q0 = 3; q1 = 4; q2 = 5; }
    else              { q0 = 4; q1 = 5; q2 = 6; }

    const float* xb = x + (size_t)b * (1792 * 28);
    for (int bt = 0; bt < 3; ++bt) {
        float4 vbuf[7];
#pragma unroll
        for (int u = 0; u < 7; ++u) {
            int f  = tid + (((bt * 7) + u) << 8);
            int R  = f / 3;
            int q3 = f - R * 3;
            int q  = (q3 == 0) ? q0 : ((q3 == 1) ? q1 : q2);
            vbuf[u] = *reinterpret_cast<const float4*>(xb + R * 28 + (q << 2));
        }
#pragma unroll
        for (int u = 0; u < 7; ++u) {
            int f  = tid + (((bt * 7) + u) << 8);
            int R  = f / 3;
            int q3 = f - R * 3;
            int q  = (q3 == 0) ? q0 : ((q3 == 1) ? q1 : q2);
            int a  = R % 28;
            int j2 = (R / 28) << 1;
            float vv[4] = {vbuf[u].x, vbuf[u].y, vbuf[u].z, vbuf[u].w};
#pragma unroll
            for (int e = 0; e < 4; ++e) {
                int n = (q << 2) + e;
                int sl; bool ok;
                if (bc == 0) {
                    if (n < 8)        { sl = n + 1;  ok = true; }
                    else if (n >= 26) { sl = n - 17; ok = true; }
                    else              { sl = 0;      ok = false; }
                } else {
                    sl = n + 2 - c0;
                    ok = (unsigned)sl < 10u;
                }
                if (ok) {
                    int row  = a * 13 + sl;
                    int byte = (row << 7) + (j2 ^ ((row & 7) << 4));
                    *(unsigned short*)(smem + byte) = f2b(vv[e]);
                }
            }
        }
    }
    __syncthreads();

    // ---- K-loop: per wave 14 m-tiles x 2 n-tiles, 6 K-steps of 32 ----
    const int cl = rl & 7;
    const int rh = rl >> 3;
    int rowoff[3];
#pragma unroll
    for (int k = 0; k < 3; ++k) {
        int sIdx = (bc == 0) ? ((cl == 0) ? (9 + k) : (cl - 1 + k)) : (cl + k);
        rowoff[k] = rh * 13 + sIdx;
    }

    f32x4 acc[14][2];
#pragma unroll
    for (int mt = 0; mt < 14; ++mt) {
        acc[mt][0] = f32x4{0.f, 0.f, 0.f, 0.f};
        acc[mt][1] = f32x4{0.f, 0.f, 0.f, 0.f};
    }

#pragma unroll
    for (int s = 0; s < 6; ++s) {
        const int k  = s >> 1;
        const int jb = ((s & 1) << 5) + jb0;
        const int jx = jb << 1;
        bf16x8 b0 = *reinterpret_cast<const bf16x8*>(wt + (k << 13) + (((w << 5) + rl) << 6) + jb);
        bf16x8 b1 = *reinterpret_cast<const bf16x8*>(wt + (k << 13) + (((w << 5) + 16 + rl) << 6) + jb);
#pragma unroll
        for (int mt = 0; mt < 14; ++mt) {
            int row  = 26 * mt + rowoff[k];
            int byte = (row << 7) + (jx ^ ((row & 7) << 4));
            bf16x8 af = *reinterpret_cast<const bf16x8*>(smem + byte);
            acc[mt][0] = __builtin_amdgcn_mfma_f32_16x16x32_bf16(af, b0, acc[mt][0], 0, 0, 0);
            acc[mt][1] = __builtin_amdgcn_mfma_f32_16x16x32_bf16(af, b1, acc[mt][1], 0, 0, 0);
        }
    }
    __syncthreads();

    // ---- epilogue writes: t4s[ic][cl][l], scalar b16 at ~2-way banks (free) ----
    {
        const int rq  = (lane >> 4) << 2;
        const int icb = (w << 5) + rl;
#pragma unroll
        for (int mt = 0; mt < 14; ++mt) {
            int rbase = (mt << 4) + rq;
            int a     = rbase >> 3;                 // 2mt + (rq>=8)
            int l     = (a == 27) ? 0 : (a + 1);    // roll applied at write
            int l2    = l << 1;
            int clb   = rbase & 7;                  // 0 or 4
#pragma unroll
            for (int p = 0; p < 2; ++p) {
                int ic   = icb + (p << 4);
                int base = (ic << 9);
                int ic7  = ic * 7;
#pragma unroll
                for (int q = 0; q < 4; ++q) {
                    int cc   = clb + q;
                    int byte = base + (cc << 6) + (l2 ^ (((ic7 + cc) & 7) << 3));
                    *(unsigned short*)(smem + byte) = f2b(acc[mt][p][q]);
                }
            }
        }
    }
    __syncthreads();

    // ---- combine with w0: 2 x ds_read_b64 per output float4; nt stores ----
    for (int f = tid; f < 6272; f += 256) {
        int lq    = f % 7;
        int t1    = f / 7;
        int m_loc = t1 % 7;
        int iloc  = t1 / 7;                     // 0..127
        float w00 = w0s[2 * iloc], w01 = w0s[2 * iloc + 1];
        int m     = c0 + m_loc;
        int lo    = lq << 3;                    // l-run byte offset (l = lq*4..lq*4+3)
        int i7    = iloc * 7;
        int cl1   = m_loc + 1;                  // c = m
        int cl2   = m_loc;                      // c = m-1
        int by1   = (iloc << 9) + (cl1 << 6) + (lo ^ (((i7 + cl1) & 7) << 3));
        int by2   = (iloc << 9) + (cl2 << 6) + (lo ^ (((i7 + cl2) & 7) << 3));
        u16x4 h1  = *reinterpret_cast<const u16x4*>(smem + by1);
        u16x4 h2  = *reinterpret_cast<const u16x4*>(smem + by2);
        f32x4 o;
        o.x = w00 * b2f(h1.x) + w01 * b2f(h2.x);
        o.y = w00 * b2f(h1.y) + w01 * b2f(h2.y);
        o.z = w00 * b2f(h1.z) + w01 * b2f(h2.z);
        o.w = w00 * b2f(h1.w) + w01 * b2f(h2.w);
        __builtin_nontemporal_store(
            o, reinterpret_cast<f32x4*>(y + ((((size_t)b * 128 + iloc) * 28 + m) * 28) + (lq << 2)));
    }
}

extern "C" void kernel_launch(void* const* d_in, const int* in_sizes, int n_in,
                              void* d_out, int out_size, void* d_ws, size_t ws_size,
                              hipStream_t stream) {
    const float* x  = (const float*)d_in[0];
    const float* w0 = (const float*)d_in[1];
    const float* w1 = (const float*)d_in[2];
    float* y = (float*)d_out;
    unsigned short* wt = (unsigned short*)d_ws;   // 24576 u16 = 48 KiB

    hipLaunchKernelGGL(wt_prepass, dim3(96), dim3(256), 0, stream, w1, wt);
    hipLaunchKernelGGL(fused_main, dim3(4096), dim3(256), 0, stream, x, w0, wt, y);
}